// Round 11
// baseline (184.244 us; speedup 1.0000x reference)
//
#include <hip/hip_runtime.h>
#include <hip/hip_fp16.h>

#define D_FEAT 128
#define NBINS_MAX 10
#define BIN_SIZE 10000      // nodes per bin: 40 KB lacc + 40 KB pos = 80 KB LDS
#define PB 4000             // prep blocks (bucket segments per bin)
#define PB_THREADS 256
#define CAP 256             // slots per (bin, prep-block); mean 160, +7.6 sigma
#define CAP_SHIFT 8
#define SBB 50              // scatter sub-blocks per bin -> grid 500 <= 512 (one round)
#define SEGS (PB / SBB)     // 80 prep segments per scatter block
#define SC_THREADS 1024
#define DIST_SCALE 1024.0f
#define INV_DIST_SCALE (1.0f / 1024.0f)

__global__ void init_pos(const float* __restrict__ h, float* __restrict__ pos, int n) {
    int i = blockIdx.x * blockDim.x + threadIdx.x;
    if (i < n) pos[i] = h[(size_t)i * D_FEAT];
}

// Counting-sort edges into (bin, prep-block) buckets AND fold in the pos[src]
// gather: pv word = (fp16(pos[src]) << 14) | d_rel  (30 bits). Scatter then
// never gathers. Gathers here overlap the edge stream at 8 blocks/CU.
__global__ __launch_bounds__(PB_THREADS, 8) void prep_kernel(
        const int* __restrict__ src, const int* __restrict__ dst,
        const float* __restrict__ pos,
        unsigned int* __restrict__ pv2, unsigned int* __restrict__ cnts,
        int n_edges, int nbins, int chunk) {
    __shared__ unsigned int cursor[NBINS_MAX];
    const int b = blockIdx.x;
    const int t = threadIdx.x;
    if (t < nbins) cursor[t] = 0u;
    __syncthreads();

    const long base = (long)b * chunk;
    long lim = (long)n_edges - base;
    if (lim > chunk) lim = chunk;
    if (lim < 0) lim = 0;

#define PREP_ONE(dd, aa)                                                        \
    {                                                                           \
        unsigned int d = (unsigned int)(dd);                                    \
        unsigned int bin = d / BIN_SIZE;                                        \
        unsigned int drel = d - bin * BIN_SIZE;                                 \
        unsigned int hb = (unsigned int)__half_as_ushort(__float2half(aa));     \
        unsigned int slot = atomicAdd(&cursor[bin], 1u);                        \
        if (slot < CAP)                                                         \
            pv2[(((size_t)bin * PB + b) << CAP_SHIFT) + slot] =                 \
                (hb << 14) | drel;                                              \
    }

    int k4 = (int)(lim & ~3L);
    for (int k = t * 4; k < k4; k += PB_THREADS * 4) {
        int4 d4 = *(const int4*)(dst + base + k);
        int4 s4 = *(const int4*)(src + base + k);
        // issue all 4 gathers first (independent, in flight together)
        float a0 = pos[s4.x];
        float a1 = pos[s4.y];
        float a2 = pos[s4.z];
        float a3 = pos[s4.w];
        PREP_ONE(d4.x, a0);
        PREP_ONE(d4.y, a1);
        PREP_ONE(d4.z, a2);
        PREP_ONE(d4.w, a3);
    }
    for (long k = k4 + t; k < lim; k += PB_THREADS) {
        float a = pos[src[k]];
        PREP_ONE(dst[k], a);
    }
#undef PREP_ONE
    __syncthreads();
    if (t < nbins) {
        unsigned int c = cursor[t];
        cnts[t * PB + b] = c < CAP ? c : CAP;
    }
}

// Pure-streaming scatter: read pv (fp16 src-pos embedded), LDS-only lookups
// and atomics, write partial slice. No global gathers at all.
// Coverage: every part[j][bin_lo..bin_lo+bin_n) written unconditionally.
__global__ __launch_bounds__(SC_THREADS) void scatter_kernel(
        const unsigned int* __restrict__ pv2, const unsigned int* __restrict__ cnts,
        const float* __restrict__ pos, unsigned int* __restrict__ part,
        int n_nodes) {
    __shared__ unsigned int lacc[BIN_SIZE];
    __shared__ float pos_lds[BIN_SIZE];
    __shared__ unsigned int cl[SEGS];
    const int bx = blockIdx.x;
    const int bin = bx / SBB;
    const int j = bx - bin * SBB;
    const int bin_lo = bin * BIN_SIZE;
    const int bin_n = min(BIN_SIZE, n_nodes - bin_lo);
    const int t = threadIdx.x;

    if (t < SEGS) cl[t] = cnts[bin * PB + j * SEGS + t];
    for (int k = t; k < bin_n; k += SC_THREADS) {
        lacc[k] = 0u;
        pos_lds[k] = pos[bin_lo + k];
    }
    __syncthreads();

#define SC_BODY(vv)                                                             \
    {                                                                           \
        float a = __half2float(__ushort_as_half((unsigned short)((vv) >> 14))); \
        unsigned int r = (vv) & 0x3FFFu;                                        \
        unsigned int f = min((unsigned int)(fabsf(a - pos_lds[r]) * DIST_SCALE + 0.5f), 16383u); \
        atomicAdd(&lacc[r], (1u << 24) | f);                                    \
    }

    const unsigned int* pj = pv2 + (((size_t)bin * PB + (size_t)j * SEGS) << CAP_SHIFT);
    const int TOT = SEGS * CAP;              // 20480
    for (int idx = t * 8; idx < TOT; idx += SC_THREADS * 8) {
        int seg = idx >> CAP_SHIFT;
        int slot = idx & (CAP - 1);          // 8-aligned, stays within seg
        int cnt = (int)cl[seg];
        const unsigned int* p = pj + ((size_t)seg << CAP_SHIFT);
        if (slot + 8 <= cnt) {
            uint4 va = *(const uint4*)(p + slot);
            uint4 vb = *(const uint4*)(p + slot + 4);
            SC_BODY(va.x); SC_BODY(va.y); SC_BODY(va.z); SC_BODY(va.w);
            SC_BODY(vb.x); SC_BODY(vb.y); SC_BODY(vb.z); SC_BODY(vb.w);
        } else if (slot < cnt) {
            for (int q = slot; q < cnt && q < slot + 8; ++q) SC_BODY(p[q]);
        }
    }
#undef SC_BODY
    __syncthreads();

    unsigned int* slice = part + (size_t)j * n_nodes + bin_lo;
    for (int k = t; k < bin_n; k += SC_THREADS) slice[k] = lacc[k];
}

// 4 nodes per thread, uint4 per slice row, float4 stores.
__global__ void merge_kernel(const float* __restrict__ pos,
                             const unsigned int* __restrict__ part,
                             float* __restrict__ out, int n_nodes) {
    int i0 = (blockIdx.x * blockDim.x + threadIdx.x) * 4;
    if (i0 + 4 <= n_nodes) {
        unsigned int c0 = 0, c1 = 0, c2 = 0, c3 = 0;
        unsigned int s0 = 0, s1 = 0, s2 = 0, s3 = 0;
        for (int b = 0; b < SBB; ++b) {
            uint4 p = *(const uint4*)(part + (size_t)b * n_nodes + i0);
            c0 += p.x >> 24; s0 += p.x & 0x00FFFFFFu;
            c1 += p.y >> 24; s1 += p.y & 0x00FFFFFFu;
            c2 += p.z >> 24; s2 += p.z & 0x00FFFFFFu;
            c3 += p.w >> 24; s3 += p.w & 0x00FFFFFFu;
        }
        float4 ps = *(const float4*)(pos + i0);
        float4 oa, ob;
        oa.x = ps.x; oa.y = ((float)s0 * INV_DIST_SCALE) / fmaxf((float)c0, 1.0f);
        oa.z = ps.y; oa.w = ((float)s1 * INV_DIST_SCALE) / fmaxf((float)c1, 1.0f);
        ob.x = ps.z; ob.y = ((float)s2 * INV_DIST_SCALE) / fmaxf((float)c2, 1.0f);
        ob.z = ps.w; ob.w = ((float)s3 * INV_DIST_SCALE) / fmaxf((float)c3, 1.0f);
        ((float4*)out)[(i0 >> 1)] = oa;
        ((float4*)out)[(i0 >> 1) + 1] = ob;
    } else {
        for (int i = i0; i < n_nodes; ++i) {
            unsigned int cnt = 0, sum = 0;
            for (int b = 0; b < SBB; ++b) {
                unsigned int p = part[(size_t)b * n_nodes + i];
                cnt += p >> 24;
                sum += p & 0x00FFFFFFu;
            }
            float2 o;
            o.x = pos[i];
            o.y = ((float)sum * INV_DIST_SCALE) / fmaxf((float)cnt, 1.0f);
            ((float2*)out)[i] = o;
        }
    }
}

// ---------- fallback path (small ws): packed u64 global atomics ----------
__global__ void fb_init(const float* __restrict__ h, float* __restrict__ pos,
                        unsigned long long* __restrict__ acc, int n) {
    int i = blockIdx.x * blockDim.x + threadIdx.x;
    if (i < n) { pos[i] = h[(size_t)i * D_FEAT]; acc[i] = 0ull; }
}
__global__ void fb_edge(const int* __restrict__ src, const int* __restrict__ dst,
                        const float* __restrict__ pos,
                        unsigned long long* __restrict__ acc, int n_edges) {
    int stride = gridDim.x * blockDim.x;
    for (int i = blockIdx.x * blockDim.x + threadIdx.x; i < n_edges; i += stride) {
        float dist = fabsf(pos[src[i]] - pos[dst[i]]);
        unsigned int fx = (unsigned int)(dist * 262144.0f + 0.5f);
        atomicAdd(&acc[dst[i]], (1ull << 32) | (unsigned long long)fx);
    }
}
__global__ void fb_final(const float* __restrict__ pos,
                         const unsigned long long* __restrict__ acc,
                         float* __restrict__ out, int n) {
    int i = blockIdx.x * blockDim.x + threadIdx.x;
    if (i < n) {
        unsigned long long v = acc[i];
        unsigned int cnt = (unsigned int)(v >> 32);
        float s = (float)(unsigned int)(v & 0xffffffffull) * (1.0f / 262144.0f);
        float2 o; o.x = pos[i]; o.y = s / fmaxf((float)cnt, 1.0f);
        ((float2*)out)[i] = o;
    }
}

extern "C" void kernel_launch(void* const* d_in, const int* in_sizes, int n_in,
                              void* d_out, int out_size, void* d_ws, size_t ws_size,
                              hipStream_t stream) {
    const float* h = (const float*)d_in[0];
    const int* src = (const int*)d_in[1];
    const int* dst = (const int*)d_in[2];
    float* out = (float*)d_out;

    int n_nodes = in_sizes[0] / D_FEAT;   // 100000
    int n_edges = in_sizes[1];            // 6400000

    int chunk = (n_edges + PB - 1) / PB;                      // 1600
    int nbins = (n_nodes + BIN_SIZE - 1) / BIN_SIZE;          // 10
    size_t pos_bytes  = ((size_t)n_nodes * 4 + 255) & ~(size_t)255;
    size_t pv2_bytes  = (((size_t)nbins * PB << CAP_SHIFT) * 4 + 255) & ~(size_t)255; // 41 MB
    size_t cnts_bytes = ((size_t)nbins * PB * 4 + 255) & ~(size_t)255;                // 160 KB
    size_t part_bytes = (size_t)SBB * n_nodes * 4;                                    // 20 MB
    bool fast_ok = (ws_size >= pos_bytes + pv2_bytes + cnts_bytes + part_bytes) &&
                   (n_nodes <= (1 << 17)) && (nbins <= NBINS_MAX) &&
                   ((size_t)chunk * 10 <= (size_t)CAP * nbins * 7);

    int block = 256;
    int ngrid = (n_nodes + block - 1) / block;

    if (fast_ok) {
        char* w = (char*)d_ws;
        float* pos = (float*)w;                          w += pos_bytes;
        unsigned int* pv2 = (unsigned int*)w;            w += pv2_bytes;
        unsigned int* cnts = (unsigned int*)w;           w += cnts_bytes;
        unsigned int* part = (unsigned int*)w;
        init_pos<<<ngrid, block, 0, stream>>>(h, pos, n_nodes);
        prep_kernel<<<PB, PB_THREADS, 0, stream>>>(src, dst, pos, pv2, cnts,
                                                   n_edges, nbins, chunk);
        scatter_kernel<<<nbins * SBB, SC_THREADS, 0, stream>>>(pv2, cnts, pos,
                                                               part, n_nodes);
        int mgrid = (n_nodes + block * 4 - 1) / (block * 4);
        merge_kernel<<<mgrid, block, 0, stream>>>(pos, part, out, n_nodes);
    } else {
        float* pos = (float*)d_ws;
        unsigned long long* acc = (unsigned long long*)((char*)d_ws + pos_bytes);
        fb_init<<<ngrid, block, 0, stream>>>(h, pos, acc, n_nodes);
        fb_edge<<<(n_edges + block - 1) / block, block, 0, stream>>>(src, dst, pos, acc, n_edges);
        fb_final<<<ngrid, block, 0, stream>>>(pos, acc, out, n_nodes);
    }
}

// Round 12
// 173.646 us; speedup vs baseline: 1.0610x; 1.0610x over previous
//
#include <hip/hip_runtime.h>
#include <hip/hip_fp16.h>

#define D_FEAT 128
#define NBINS_MAX 10
#define BIN_SIZE 10000      // nodes per bin: 40 KB lacc + 40 KB pos = 80 KB LDS
#define PB 1000             // prep blocks; chunk = 6400 -> 25 edges/thread (deep MLP)
#define PB_THREADS 256
#define CAP 1024            // slots per (bin, prep-block); mean 640, sigma ~25 -> +15 sigma
#define CAP_SHIFT 10
#define SBB 50              // scatter sub-blocks per bin -> grid 500 <= 512 (one round)
#define SEGS (PB / SBB)     // 20 prep segments per scatter block
#define SC_THREADS 1024
#define DIST_SCALE 1024.0f
#define INV_DIST_SCALE (1.0f / 1024.0f)

__global__ void init_pos(const float* __restrict__ h, float* __restrict__ pos, int n) {
    int i = blockIdx.x * blockDim.x + threadIdx.x;
    if (i < n) pos[i] = h[(size_t)i * D_FEAT];
}

// Counting-sort edges into (bin, prep-block) buckets with the pos[src] gather
// folded in: pv word = (fp16(pos[src]) << 14) | d_rel. 8-deep software
// pipeline: 8 edge loads -> 8 independent gathers in flight -> 8 pushes.
__global__ __launch_bounds__(PB_THREADS, 8) void prep_kernel(
        const int* __restrict__ src, const int* __restrict__ dst,
        const float* __restrict__ pos,
        unsigned int* __restrict__ pv2, unsigned int* __restrict__ cnts,
        int n_edges, int nbins, int chunk) {
    __shared__ unsigned int cursor[NBINS_MAX];
    const int b = blockIdx.x;
    const int t = threadIdx.x;
    if (t < nbins) cursor[t] = 0u;
    __syncthreads();

    const long base = (long)b * chunk;
    long lim = (long)n_edges - base;
    if (lim > chunk) lim = chunk;
    if (lim < 0) lim = 0;

#define PREP_ONE(dd, aa)                                                        \
    {                                                                           \
        unsigned int d = (unsigned int)(dd);                                    \
        unsigned int bin = d / BIN_SIZE;                                        \
        unsigned int drel = d - bin * BIN_SIZE;                                 \
        unsigned int hb = (unsigned int)__half_as_ushort(__float2half(aa));     \
        unsigned int slot = atomicAdd(&cursor[bin], 1u);                        \
        if (slot < CAP)                                                         \
            pv2[(((size_t)bin * PB + b) << CAP_SHIFT) + slot] =                 \
                (hb << 14) | drel;                                              \
    }

    const long R = (lim / (PB_THREADS * 8)) * (PB_THREADS * 8);
    for (long k0 = (long)t * 8; k0 < R; k0 += PB_THREADS * 8) {
        const int* dp = dst + base + k0;
        const int* sp = src + base + k0;
        int4 da = *(const int4*)dp;
        int4 db = *(const int4*)(dp + 4);
        int4 sa = *(const int4*)sp;
        int4 sb = *(const int4*)(sp + 4);
        // 8 independent gathers issued back-to-back (all in flight together)
        float a0 = pos[sa.x];
        float a1 = pos[sa.y];
        float a2 = pos[sa.z];
        float a3 = pos[sa.w];
        float a4 = pos[sb.x];
        float a5 = pos[sb.y];
        float a6 = pos[sb.z];
        float a7 = pos[sb.w];
        PREP_ONE(da.x, a0);
        PREP_ONE(da.y, a1);
        PREP_ONE(da.z, a2);
        PREP_ONE(da.w, a3);
        PREP_ONE(db.x, a4);
        PREP_ONE(db.y, a5);
        PREP_ONE(db.z, a6);
        PREP_ONE(db.w, a7);
    }
    for (long k = R + t; k < lim; k += PB_THREADS) {
        float a = pos[src[base + k]];
        PREP_ONE(dst[base + k], a);
    }
#undef PREP_ONE
    __syncthreads();
    if (t < nbins) {
        unsigned int c = cursor[t];
        cnts[t * PB + b] = c < CAP ? c : CAP;
    }
}

// Pure-streaming scatter: read pv (fp16 src-pos embedded), LDS-only lookups
// and atomics, write partial slice. No global gathers at all.
// Coverage: every part[j][bin_lo..bin_lo+bin_n) written unconditionally.
__global__ __launch_bounds__(SC_THREADS) void scatter_kernel(
        const unsigned int* __restrict__ pv2, const unsigned int* __restrict__ cnts,
        const float* __restrict__ pos, unsigned int* __restrict__ part,
        int n_nodes) {
    __shared__ unsigned int lacc[BIN_SIZE];
    __shared__ float pos_lds[BIN_SIZE];
    __shared__ unsigned int cl[SEGS];
    const int bx = blockIdx.x;
    const int bin = bx / SBB;
    const int j = bx - bin * SBB;
    const int bin_lo = bin * BIN_SIZE;
    const int bin_n = min(BIN_SIZE, n_nodes - bin_lo);
    const int t = threadIdx.x;

    if (t < SEGS) cl[t] = cnts[bin * PB + j * SEGS + t];
    for (int k = t; k < bin_n; k += SC_THREADS) {
        lacc[k] = 0u;
        pos_lds[k] = pos[bin_lo + k];
    }
    __syncthreads();

#define SC_BODY(vv)                                                             \
    {                                                                           \
        float a = __half2float(__ushort_as_half((unsigned short)((vv) >> 14))); \
        unsigned int r = (vv) & 0x3FFFu;                                        \
        unsigned int f = min((unsigned int)(fabsf(a - pos_lds[r]) * DIST_SCALE + 0.5f), 16383u); \
        atomicAdd(&lacc[r], (1u << 24) | f);                                    \
    }

    const unsigned int* pj = pv2 + (((size_t)bin * PB + (size_t)j * SEGS) << CAP_SHIFT);
    const int TOT = SEGS * CAP;              // 20480
    for (int idx = t * 8; idx < TOT; idx += SC_THREADS * 8) {
        int seg = idx >> CAP_SHIFT;
        int slot = idx & (CAP - 1);          // 8-aligned, stays within seg
        int cnt = (int)cl[seg];
        const unsigned int* p = pj + ((size_t)seg << CAP_SHIFT);
        if (slot + 8 <= cnt) {
            uint4 va = *(const uint4*)(p + slot);
            uint4 vb = *(const uint4*)(p + slot + 4);
            SC_BODY(va.x); SC_BODY(va.y); SC_BODY(va.z); SC_BODY(va.w);
            SC_BODY(vb.x); SC_BODY(vb.y); SC_BODY(vb.z); SC_BODY(vb.w);
        } else if (slot < cnt) {
            for (int q = slot; q < cnt && q < slot + 8; ++q) SC_BODY(p[q]);
        }
    }
#undef SC_BODY
    __syncthreads();

    unsigned int* slice = part + (size_t)j * n_nodes + bin_lo;
    for (int k = t; k < bin_n; k += SC_THREADS) slice[k] = lacc[k];
}

// 4 nodes per thread, uint4 per slice row, float4 stores.
__global__ void merge_kernel(const float* __restrict__ pos,
                             const unsigned int* __restrict__ part,
                             float* __restrict__ out, int n_nodes) {
    int i0 = (blockIdx.x * blockDim.x + threadIdx.x) * 4;
    if (i0 + 4 <= n_nodes) {
        unsigned int c0 = 0, c1 = 0, c2 = 0, c3 = 0;
        unsigned int s0 = 0, s1 = 0, s2 = 0, s3 = 0;
        for (int b = 0; b < SBB; ++b) {
            uint4 p = *(const uint4*)(part + (size_t)b * n_nodes + i0);
            c0 += p.x >> 24; s0 += p.x & 0x00FFFFFFu;
            c1 += p.y >> 24; s1 += p.y & 0x00FFFFFFu;
            c2 += p.z >> 24; s2 += p.z & 0x00FFFFFFu;
            c3 += p.w >> 24; s3 += p.w & 0x00FFFFFFu;
        }
        float4 ps = *(const float4*)(pos + i0);
        float4 oa, ob;
        oa.x = ps.x; oa.y = ((float)s0 * INV_DIST_SCALE) / fmaxf((float)c0, 1.0f);
        oa.z = ps.y; oa.w = ((float)s1 * INV_DIST_SCALE) / fmaxf((float)c1, 1.0f);
        ob.x = ps.z; ob.y = ((float)s2 * INV_DIST_SCALE) / fmaxf((float)c2, 1.0f);
        ob.z = ps.w; ob.w = ((float)s3 * INV_DIST_SCALE) / fmaxf((float)c3, 1.0f);
        ((float4*)out)[(i0 >> 1)] = oa;
        ((float4*)out)[(i0 >> 1) + 1] = ob;
    } else {
        for (int i = i0; i < n_nodes; ++i) {
            unsigned int cnt = 0, sum = 0;
            for (int b = 0; b < SBB; ++b) {
                unsigned int p = part[(size_t)b * n_nodes + i];
                cnt += p >> 24;
                sum += p & 0x00FFFFFFu;
            }
            float2 o;
            o.x = pos[i];
            o.y = ((float)sum * INV_DIST_SCALE) / fmaxf((float)cnt, 1.0f);
            ((float2*)out)[i] = o;
        }
    }
}

// ---------- fallback path (small ws): packed u64 global atomics ----------
__global__ void fb_init(const float* __restrict__ h, float* __restrict__ pos,
                        unsigned long long* __restrict__ acc, int n) {
    int i = blockIdx.x * blockDim.x + threadIdx.x;
    if (i < n) { pos[i] = h[(size_t)i * D_FEAT]; acc[i] = 0ull; }
}
__global__ void fb_edge(const int* __restrict__ src, const int* __restrict__ dst,
                        const float* __restrict__ pos,
                        unsigned long long* __restrict__ acc, int n_edges) {
    int stride = gridDim.x * blockDim.x;
    for (int i = blockIdx.x * blockDim.x + threadIdx.x; i < n_edges; i += stride) {
        float dist = fabsf(pos[src[i]] - pos[dst[i]]);
        unsigned int fx = (unsigned int)(dist * 262144.0f + 0.5f);
        atomicAdd(&acc[dst[i]], (1ull << 32) | (unsigned long long)fx);
    }
}
__global__ void fb_final(const float* __restrict__ pos,
                         const unsigned long long* __restrict__ acc,
                         float* __restrict__ out, int n) {
    int i = blockIdx.x * blockDim.x + threadIdx.x;
    if (i < n) {
        unsigned long long v = acc[i];
        unsigned int cnt = (unsigned int)(v >> 32);
        float s = (float)(unsigned int)(v & 0xffffffffull) * (1.0f / 262144.0f);
        float2 o; o.x = pos[i]; o.y = s / fmaxf((float)cnt, 1.0f);
        ((float2*)out)[i] = o;
    }
}

extern "C" void kernel_launch(void* const* d_in, const int* in_sizes, int n_in,
                              void* d_out, int out_size, void* d_ws, size_t ws_size,
                              hipStream_t stream) {
    const float* h = (const float*)d_in[0];
    const int* src = (const int*)d_in[1];
    const int* dst = (const int*)d_in[2];
    float* out = (float*)d_out;

    int n_nodes = in_sizes[0] / D_FEAT;   // 100000
    int n_edges = in_sizes[1];            // 6400000

    int chunk = (n_edges + PB - 1) / PB;                      // 6400
    int nbins = (n_nodes + BIN_SIZE - 1) / BIN_SIZE;          // 10
    size_t pos_bytes  = ((size_t)n_nodes * 4 + 255) & ~(size_t)255;
    size_t pv2_bytes  = (((size_t)nbins * PB << CAP_SHIFT) * 4 + 255) & ~(size_t)255; // 41 MB
    size_t cnts_bytes = ((size_t)nbins * PB * 4 + 255) & ~(size_t)255;                // 40 KB
    size_t part_bytes = (size_t)SBB * n_nodes * 4;                                    // 20 MB
    bool fast_ok = (ws_size >= pos_bytes + pv2_bytes + cnts_bytes + part_bytes) &&
                   (n_nodes <= (1 << 17)) && (nbins <= NBINS_MAX) &&
                   ((size_t)chunk * 10 <= (size_t)CAP * nbins * 7);

    int block = 256;
    int ngrid = (n_nodes + block - 1) / block;

    if (fast_ok) {
        char* w = (char*)d_ws;
        float* pos = (float*)w;                          w += pos_bytes;
        unsigned int* pv2 = (unsigned int*)w;            w += pv2_bytes;
        unsigned int* cnts = (unsigned int*)w;           w += cnts_bytes;
        unsigned int* part = (unsigned int*)w;
        init_pos<<<ngrid, block, 0, stream>>>(h, pos, n_nodes);
        prep_kernel<<<PB, PB_THREADS, 0, stream>>>(src, dst, pos, pv2, cnts,
                                                   n_edges, nbins, chunk);
        scatter_kernel<<<nbins * SBB, SC_THREADS, 0, stream>>>(pv2, cnts, pos,
                                                               part, n_nodes);
        int mgrid = (n_nodes + block * 4 - 1) / (block * 4);
        merge_kernel<<<mgrid, block, 0, stream>>>(pos, part, out, n_nodes);
    } else {
        float* pos = (float*)d_ws;
        unsigned long long* acc = (unsigned long long*)((char*)d_ws + pos_bytes);
        fb_init<<<ngrid, block, 0, stream>>>(h, pos, acc, n_nodes);
        fb_edge<<<(n_edges + block - 1) / block, block, 0, stream>>>(src, dst, pos, acc, n_edges);
        fb_final<<<ngrid, block, 0, stream>>>(pos, acc, out, n_nodes);
    }
}